// Round 2
// baseline (430.829 us; speedup 1.0000x reference)
//
#include <hip/hip_runtime.h>
#include <hip/hip_bf16.h>

#define FEAT 128
#define NRELS 8
#define KTOT 1024          // NRELS * FEAT
#define BN 32              // dst nodes per aggemm block
#define SCAN2 1024

typedef __bf16 bf16_t;
typedef __bf16 bf16x2_t __attribute__((ext_vector_type(2)));
typedef __bf16 bf16x4_t __attribute__((ext_vector_type(4)));
typedef __bf16 bf16x8_t __attribute__((ext_vector_type(8)));
typedef float f32x4 __attribute__((ext_vector_type(4)));

struct __align__(8) PackedEdge { int row; float scale; };  // row = (src<<3)|rel

static inline size_t align256(size_t x) { return (x + 255) & ~(size_t)255; }

// ---------------------------------------------------------------------------
// w [R][d][f] fp32 -> wt2 [f][r][d] bf16 : GEMM B-operand, k=(r,d) contiguous
// per f row (k = r*128 + d). 256 KiB total, L2-resident during GEMM.
__global__ void k_convert_w2(const float* __restrict__ w, bf16_t* __restrict__ wt2) {
    int i = blockIdx.x * blockDim.x + threadIdx.x;
    if (i >= NRELS * FEAT * FEAT) return;
    int r = i >> 14;
    int rem = i & 16383;
    int d = rem >> 7;
    int f = rem & 127;
    wt2[(size_t)f * KTOT + r * FEAT + d] = (bf16_t)w[i];
}

// ---------------------------------------------------------------------------
// h fp32 -> hb bf16 [N][128]. 25.6 MB -> L3-resident for the edge gathers.
__global__ void k_convert_h(const float* __restrict__ h, bf16x4_t* __restrict__ hb4,
                            int ntotal) {
    int i = blockIdx.x * blockDim.x + threadIdx.x;
    if (i >= ntotal * (FEAT / 4)) return;
    float4 v = reinterpret_cast<const float4*>(h)[i];
    bf16x4_t o;
    o.x = (bf16_t)v.x; o.y = (bf16_t)v.y; o.z = (bf16_t)v.z; o.w = (bf16_t)v.w;
    hb4[i] = o;
}

// ---------------------------------------------------------------------------
// Gate: sg[n][r] = sigmoid(sum_d h[n][d]*gw[r][d]); fp32. One wave per node.
__global__ void k_gate(const float* __restrict__ h, const float* __restrict__ gw,
                       float* __restrict__ sg, int ncount) {
    int wv = (int)((blockIdx.x * blockDim.x + threadIdx.x) >> 6);
    int lane = threadIdx.x & 63;
    if (wv >= ncount) return;
    float2 hv = *reinterpret_cast<const float2*>(h + (size_t)wv * FEAT + lane * 2);
    float res[NRELS];
#pragma unroll
    for (int r = 0; r < NRELS; ++r) {
        float2 wvv = *reinterpret_cast<const float2*>(gw + r * FEAT + lane * 2);
        float s = hv.x * wvv.x + hv.y * wvv.y;
#pragma unroll
        for (int off = 32; off; off >>= 1) s += __shfl_xor(s, off, 64);
        res[r] = s;
    }
    if (lane == 0) {
#pragma unroll
        for (int r = 0; r < NRELS; ++r)
            sg[(size_t)wv * NRELS + r] = 1.0f / (1.0f + __expf(-res[r]));
    }
}

// ---------------------------------------------------------------------------
// CSR build keyed by (dst, rel): 8*N segments -> per-node edges arrive
// rel-sorted, so the aggregator needs only ONE live accumulator per wave.
__global__ void k_degree8(const int* __restrict__ dstv, const int* __restrict__ rel,
                          int* __restrict__ deg8, int nedges) {
    int e = blockIdx.x * blockDim.x + threadIdx.x;
    if (e >= nedges) return;
    atomicAdd(&deg8[(dstv[e] << 3) | rel[e]], 1);
}

// 1024-wide scan chunks (n up to 1024*1024 with single tops pass).
__global__ __launch_bounds__(1024) void k_scan_block2(const int* __restrict__ in,
                                                      int* __restrict__ outv,
                                                      int* __restrict__ bsum, int n) {
    __shared__ int sm[1024];
    int t = threadIdx.x;
    int idx = blockIdx.x * SCAN2 + t;
    int v = (idx < n) ? in[idx] : 0;
    sm[t] = v;
    __syncthreads();
    for (int off = 1; off < 1024; off <<= 1) {
        int x = (t >= off) ? sm[t - off] : 0;
        __syncthreads();
        sm[t] += x;
        __syncthreads();
    }
    if (idx < n) outv[idx] = sm[t] - v;
    if (t == 1023) bsum[blockIdx.x] = sm[1023];
}

__global__ __launch_bounds__(1024) void k_scan_tops(int* __restrict__ bsum, int nb,
                                                    int* __restrict__ rowptr_end) {
    __shared__ int sm[1024];
    int t = threadIdx.x;
    if (nb <= 1024) {
        int v = (t < nb) ? bsum[t] : 0;
        sm[t] = v;
        __syncthreads();
        for (int off = 1; off < 1024; off <<= 1) {
            int x = (t >= off) ? sm[t - off] : 0;
            __syncthreads();
            sm[t] += x;
            __syncthreads();
        }
        if (t < nb) bsum[t] = sm[t] - v;
        if (t == 1023) *rowptr_end = sm[1023];
    } else if (t == 0) {
        int run = 0;
        for (int b = 0; b < nb; ++b) { int v = bsum[b]; bsum[b] = run; run += v; }
        *rowptr_end = run;
    }
}

__global__ void k_scan_add2(int* __restrict__ rowptr, const int* __restrict__ bsum, int n) {
    int i = blockIdx.x * blockDim.x + threadIdx.x;
    if (i >= n) return;
    rowptr[i] += bsum[i >> 10];   // SCAN2 = 1<<10
}

// Fill packed records {(src<<3)|rel, norm*sigmoid_gate} at (dst,rel)-CSR slots.
__global__ void k_fill8(const int* __restrict__ src, const int* __restrict__ dstv,
                        const int* __restrict__ rel, const float* __restrict__ nrm,
                        const float* __restrict__ sg, const int* __restrict__ rp8,
                        int* __restrict__ cursor, PackedEdge* __restrict__ packed,
                        int nedges) {
    int e = blockIdx.x * blockDim.x + threadIdx.x;
    if (e >= nedges) return;
    int d = dstv[e];
    int s = src[e];
    int r = rel[e];
    int key = (d << 3) | r;
    int pos = rp8[key] + atomicAdd(&cursor[key], 1);
    PackedEdge p;
    p.row = (s << 3) | r;
    p.scale = nrm[e] * sg[(size_t)s * NRELS + r];
    packed[pos] = p;
}

// ---------------------------------------------------------------------------
// Fused aggregate + GEMM + relu. Block = 512 threads (8 waves), 32 dst nodes.
// Phase A: wave wv aggregates nodes wv*4..wv*4+3. Per edge the full wave reads
//   one hb row (64 lanes x 2 bf16), FMA-accumulates in 2 fp32 regs; on rel
//   change (wave-uniform, edges are rel-sorted) flushes bf16x2 to the LDS agg
//   tile [32 nodes][1024 k] (k = r*128+d), XOR-swizzled at 16B chunks
//   (chunk ^ (node&7)) for conflict-free GEMM reads. Empty rels stay zero.
// Phase B: M=32,N=128,K=1024 MFMA GEMM: A-frags ds_read_b128 from LDS,
//   B-frags bf16x8 from wt2 (L2-hot). C staged to (aliased) LDS fp32 with
//   +4-dword row pad, then relu + fully-coalesced float4 stores.
__global__ __launch_bounds__(512, 2) void k_aggemm(const bf16_t* __restrict__ hb,
                                                   const bf16_t* __restrict__ wt2,
                                                   const PackedEdge* __restrict__ packed,
                                                   const int* __restrict__ rp8,
                                                   float* __restrict__ out, int nnodes) {
    __shared__ __align__(16) char lds_raw[BN * KTOT * sizeof(bf16_t)];   // 64 KiB
    float* cst = (float*)lds_raw;                 // aliased C-stage [32][132]
    const int t = threadIdx.x;
    const int wv = t >> 6;
    const int lane = t & 63;
    const int nb0 = blockIdx.x * BN;

    // zero agg tile: 64 KiB / 512 threads = 128 B each
    {
        f32x4 z = {0.f, 0.f, 0.f, 0.f};
#pragma unroll
        for (int i = 0; i < 8; ++i)
            reinterpret_cast<f32x4*>(lds_raw)[t + i * 512] = z;
    }
    __syncthreads();

    // ---------------- Phase A: aggregation ----------------
    auto flushrow = [&](int node, int r, float a0, float a1) {
        int c = r * 16 + (lane >> 2);             // 16B chunk within row
        int cp = c ^ (node & 7);
        bf16x2_t o;
        o.x = (bf16_t)a0;
        o.y = (bf16_t)a1;
        *reinterpret_cast<bf16x2_t*>(lds_raw + node * 2048 + cp * 16 + (lane & 3) * 4) = o;
    };

    for (int ln0 = 0; ln0 < 4; ++ln0) {
        int node = wv * 4 + ln0;
        int gnode = nb0 + node;
        int beg = 0, end = 0;
        if (gnode < nnodes) {
            beg = rp8[gnode * 8];
            end = rp8[gnode * 8 + 8];
        }
        int j = beg;
        PackedEdge p0 = {0, 0.f}, p1 = {0, 0.f};
        unsigned v0 = 0;
        if (j < end) p0 = packed[j];
        if (j + 1 < end) p1 = packed[j + 1];
        if (j < end)
            v0 = *reinterpret_cast<const unsigned*>(
                hb + ((size_t)(p0.row >> 3) << 7) + lane * 2);
        float a0 = 0.f, a1 = 0.f;
        int cur_r = (j < end) ? (p0.row & 7) : -1;
#pragma unroll 1
        for (; j < end; ++j) {
            unsigned v1 = 0;
            if (j + 1 < end)                       // prefetch next hb row
                v1 = *reinterpret_cast<const unsigned*>(
                    hb + ((size_t)(p1.row >> 3) << 7) + lane * 2);
            PackedEdge p2 = {0, 0.f};
            if (j + 2 < end) p2 = packed[j + 2];   // prefetch next-next record
            int r = p0.row & 7;
            if (r != cur_r) {                      // wave-uniform branch
                flushrow(node, cur_r, a0, a1);
                a0 = 0.f; a1 = 0.f;
                cur_r = r;
            }
            bf16x2_t bv = __builtin_bit_cast(bf16x2_t, v0);
            a0 += (float)bv.x * p0.scale;
            a1 += (float)bv.y * p0.scale;
            p0 = p1; p1 = p2; v0 = v1;
        }
        if (cur_r >= 0) flushrow(node, cur_r, a0, a1);
    }
    __syncthreads();

    // ---------------- Phase B: GEMM ----------------
    const int l15 = lane & 15;
    const int lhi = lane >> 4;
    f32x4 acc0 = {0.f, 0.f, 0.f, 0.f};
    f32x4 acc1 = {0.f, 0.f, 0.f, 0.f};
    const bf16_t* bp = wt2 + (size_t)(wv * 16 + l15) * KTOT + lhi * 8;
    const char* a0p = lds_raw + (size_t)l15 * 2048;        // node rows 0..15
    const char* a1p = a0p + 16 * 2048;                     // node rows 16..31
    const int sw = l15 & 7;                                // (16+l15)&7 == l15&7
#pragma unroll 4
    for (int ks = 0; ks < 32; ++ks) {
        int coff = ((ks * 4 + lhi) ^ sw) << 4;
        bf16x8_t av0 = *reinterpret_cast<const bf16x8_t*>(a0p + coff);
        bf16x8_t av1 = *reinterpret_cast<const bf16x8_t*>(a1p + coff);
        bf16x8_t bv = *reinterpret_cast<const bf16x8_t*>(bp + ks * 32);
        acc0 = __builtin_amdgcn_mfma_f32_16x16x32_bf16(av0, bv, acc0, 0, 0, 0);
        acc1 = __builtin_amdgcn_mfma_f32_16x16x32_bf16(av1, bv, acc1, 0, 0, 0);
    }
    __syncthreads();   // all A-frag reads done; safe to overwrite agg with C

    // C layout: col(l15)=f within wave slice, row(lhi*4+i)=node (m89-verified)
    {
        int f = wv * 16 + l15;
#pragma unroll
        for (int i = 0; i < 4; ++i) {
            int n0 = lhi * 4 + i;
            cst[n0 * 132 + f] = acc0[i];
            cst[(n0 + 16) * 132 + f] = acc1[i];
        }
    }
    __syncthreads();

    // relu + coalesced store: thread t -> node t>>4, feats (t&15)*8..+8
    {
        int node = t >> 4;
        int f0 = (t & 15) * 8;
        int gnode = nb0 + node;
        if (gnode < nnodes) {
            const float* cr = cst + node * 132 + f0;
            float4 o0, o1;
            o0.x = fmaxf(cr[0], 0.f); o0.y = fmaxf(cr[1], 0.f);
            o0.z = fmaxf(cr[2], 0.f); o0.w = fmaxf(cr[3], 0.f);
            o1.x = fmaxf(cr[4], 0.f); o1.y = fmaxf(cr[5], 0.f);
            o1.z = fmaxf(cr[6], 0.f); o1.w = fmaxf(cr[7], 0.f);
            float4* op = reinterpret_cast<float4*>(out + (size_t)gnode * FEAT + f0);
            op[0] = o0;
            op[1] = o1;
        }
    }
}

// ---------------------------------------------------------------------------
extern "C" void kernel_launch(void* const* d_in, const int* in_sizes, int n_in,
                              void* d_out, int out_size, void* d_ws, size_t ws_size,
                              hipStream_t stream) {
    const float* h = (const float*)d_in[0];
    const float* w = (const float*)d_in[1];
    const float* gw = (const float*)d_in[2];
    const float* nrm = (const float*)d_in[3];
    const int* src = (const int*)d_in[4];
    const int* dst = (const int*)d_in[5];
    const int* rel = (const int*)d_in[6];
    float* out = (float*)d_out;

    const int N = in_sizes[0] / FEAT;
    const int E = in_sizes[4];
    const int NSEG = N * NRELS;                       // 800K (dst,rel) segments
    const int nb2 = (NSEG + SCAN2 - 1) / SCAN2;

    char* ws = (char*)d_ws;
    const size_t wt2B = align256((size_t)FEAT * KTOT * sizeof(bf16_t));   // 256 KiB
    const size_t hbB  = align256((size_t)N * FEAT * sizeof(bf16_t));      // 25.6 MB
    const size_t sgB  = align256((size_t)N * NRELS * sizeof(float));      // 3.2 MB
    const size_t dgB  = align256((size_t)NSEG * sizeof(int));             // 3.2 MB
    const size_t rpB  = align256((size_t)(NSEG + 1) * sizeof(int));       // 3.2 MB
    const size_t bsB  = align256((size_t)nb2 * sizeof(int));
    // packed comes last

    bf16_t* wt2 = (bf16_t*)ws;
    bf16_t* hb = (bf16_t*)(ws + wt2B);
    float* sg = (float*)(ws + wt2B + hbB);
    int* deg8 = (int*)(ws + wt2B + hbB + sgB);        // reused as cursor after scan
    int* rp8 = (int*)(ws + wt2B + hbB + sgB + dgB);
    int* bsum = (int*)(ws + wt2B + hbB + sgB + dgB + rpB);
    PackedEdge* packed = (PackedEdge*)(ws + wt2B + hbB + sgB + dgB + rpB + bsB);

    k_convert_w2<<<(NRELS * FEAT * FEAT + 255) / 256, 256, 0, stream>>>(w, wt2);
    k_convert_h<<<(N * (FEAT / 4) + 255) / 256, 256, 0, stream>>>(h, (bf16x4_t*)hb, N);
    k_gate<<<(N + 3) / 4, 256, 0, stream>>>(h, gw, sg, N);

    hipMemsetAsync(deg8, 0, (size_t)NSEG * sizeof(int), stream);
    k_degree8<<<(E + 255) / 256, 256, 0, stream>>>(dst, rel, deg8, E);
    k_scan_block2<<<nb2, 1024, 0, stream>>>(deg8, rp8, bsum, NSEG);
    k_scan_tops<<<1, 1024, 0, stream>>>(bsum, nb2, rp8 + NSEG);
    k_scan_add2<<<(NSEG + 255) / 256, 256, 0, stream>>>(rp8, bsum, NSEG);
    hipMemsetAsync(deg8, 0, (size_t)NSEG * sizeof(int), stream);   // cursor
    k_fill8<<<(E + 255) / 256, 256, 0, stream>>>(src, dst, rel, nrm, sg, rp8, deg8,
                                                 packed, E);

    k_aggemm<<<(N + BN - 1) / BN, 512, 0, stream>>>(hb, wt2, packed, rp8, out, N);
}